// Round 14
// baseline (51.908 us; speedup 1.0000x reference)
//
#include <hip/hip_runtime.h>
#include <math.h>

#define NB 4096
#define NA 8
#define BN (NB*NA)   // 32768

// ws layout (u32 words)
#define OFF_SE   0            // se pack:  8 tiles * 512
#define OFF_SAP  4096         // sap pack: 8 tiles * 512
#define OFF_AV   8192         // av pack:  8 tiles * 1024
#define OFF_F1   16384        // f1 pack:  4 tiles * 1024
#define OFF_M    20480        // M pack:   8 tiles * 1024
#define OFF_U    28672        // u: 128 floats
#define OFF_W2P  28800        // conv2 weight A-frag pack: 2 ftiles * 1280 (K=160 pad)
// ws end: 31360 words

typedef short short8 __attribute__((ext_vector_type(8)));
typedef float f32x4 __attribute__((ext_vector_type(4)));

#define MFMA(a,b,c) __builtin_amdgcn_mfma_f32_16x16x32_bf16(a,b,c,0,0,0)

__device__ __forceinline__ float fast_tanh(float x){
    float e = __expf(2.0f*x);
    return 1.0f - 2.0f*__builtin_amdgcn_rcpf(e+1.0f);
}
__device__ __forceinline__ unsigned bfr(float x){
    unsigned u = __float_as_uint(x);
    return (u + 0x7fffu + ((u>>16)&1u)) >> 16;
}
__device__ __forceinline__ unsigned pk2(float lo, float hi){
    return bfr(lo) | (bfr(hi)<<16);
}
__device__ __forceinline__ float bf2f(unsigned short s){
    return __uint_as_float(((unsigned)s)<<16);
}
__device__ __forceinline__ short8 fragld(const unsigned* p){
    union { uint4 u; short8 s; } cv;
    cv.u = *(const uint4*)p;
    return cv.s;
}

// ---------------- kW: pack all weights as A-fragments (pack16 of W^T), compute M, u, w2 pack
__global__ __launch_bounds__(256) void kW(const float* __restrict__ se_w,
        const float* __restrict__ sap_w, const float* __restrict__ av_w,
        const float* __restrict__ f1_w, const float* __restrict__ qw,
        const float* __restrict__ kw, const float* __restrict__ qb,
        const float* __restrict__ w2,
        unsigned* __restrict__ ws){
    int idx = blockIdx.x*256 + threadIdx.x;
    if (idx < 4096){                       // sePk (F=64 pad, rows f2=128)
        int w = idx, tile = w>>9, rem = w&511;
        int ft = rem>>6, r2 = (rem>>2)&15, wi = rem&3;
        int f2 = tile*16 + r2, f1 = ft*8 + wi*2;
        float lo = (f1   < 42)? se_w[f1*128+f2]     : 0.f;
        float hi = (f1+1 < 42)? se_w[(f1+1)*128+f2] : 0.f;
        ws[OFF_SE + w] = pk2(lo,hi);
    } else if (idx < 8192){                // sapPk (F=64 pad, limit 47)
        int w = idx-4096, tile = w>>9, rem = w&511;
        int ft = rem>>6, r2 = (rem>>2)&15, wi = rem&3;
        int f2 = tile*16 + r2, f1 = ft*8 + wi*2;
        float lo = (f1   < 47)? sap_w[f1*128+f2]     : 0.f;
        float hi = (f1+1 < 47)? sap_w[(f1+1)*128+f2] : 0.f;
        ws[OFF_SAP + w] = pk2(lo,hi);
    } else if (idx < 16384){               // avPk (F=128)
        int w = idx-8192, tile = w>>10, rem = w&1023;
        int ft = rem>>6, r2 = (rem>>2)&15, wi = rem&3;
        int f2 = tile*16 + r2, f1 = ft*8 + wi*2;
        ws[OFF_AV + w] = pk2(av_w[f1*128+f2], av_w[(f1+1)*128+f2]);
    } else if (idx < 20480){               // f1Pk (F=128, rows f2=64)
        int w = idx-16384, tile = w>>10, rem = w&1023;
        int ft = rem>>6, r2 = (rem>>2)&15, wi = rem&3;
        int f2 = tile*16 + r2, f1 = ft*8 + wi*2;
        ws[OFF_F1 + w] = pk2(f1_w[f1*64+f2], f1_w[(f1+1)*64+f2]);
    } else if (idx < 28672){               // MPk: M[e][f2] = qw[e]·kw[f2]
        int w = idx-20480, tile = w>>10, rem = w&1023;
        int ft = rem>>6, r2 = (rem>>2)&15, wi = rem&3;
        int f2 = tile*16 + r2, e0 = ft*8 + wi*2;
        float lo=0.f, hi=0.f;
        for (int d=0; d<128; ++d){
            float kv = kw[f2*128+d];
            lo += qw[e0*128+d]*kv;
            hi += qw[(e0+1)*128+d]*kv;
        }
        ws[OFF_M + w] = pk2(lo,hi);
    } else if (idx < 28800){               // u[f] = qb·kw[f]
        int f = idx-28672;
        float a = 0.f;
        for (int d=0; d<128; ++d) a += qb[d]*kw[f*128+d];
        ((float*)ws)[OFF_U + f] = a;
    } else if (idx < 31360){               // conv2 weight A-frags: F=32, K=160 (pad from 144)
        int w = idx-28800;
        int ftile = w/1280, rem = w - ftile*1280;
        int ft = rem>>6, r2 = (rem>>2)&15, wi = rem&3;
        int f = ftile*16 + r2, k0 = ft*8 + wi*2;
        float lo = (k0   < 144)? w2[f*144+k0]   : 0.f;
        float hi = (k0+1 < 144)? w2[f*144+k0+1] : 0.f;
        ws[OFF_W2P + w] = pk2(lo,hi);
    }
}

// ---------------- kF: barrier-free per-wave conv + fused attention/SAP/AV/f1/mix ----------
// grid 512, 256 threads = 4 waves = 4 tiles = 64 agents = 8 batches per block.
__global__ __launch_bounds__(256,2) void kF(const unsigned* __restrict__ ws,
        const float* __restrict__ xin, const float* __restrict__ pos,
        const float* __restrict__ oneh, const float* __restrict__ acts,
        const float* __restrict__ pols,
        const float* __restrict__ w1, const float* __restrict__ b1,
        const float* __restrict__ b2,
        const float* __restrict__ se_b,
        const float* __restrict__ sap_b, const float* __restrict__ av_b,
        const float* __restrict__ f1_b, const float* __restrict__ f2_w,
        const float* __restrict__ f2_b,
        float* __restrict__ wout, float* __restrict__ value){
    __shared__ unsigned SM[9216];     // conv: hpk[4*1280] + w1/b1/b2 @5120 ; AB: stage[2][2048]+U1[5120]
    __shared__ unsigned stPk[4096];   // persistent state packs: A[4*512] | P[4*512]
    __shared__ unsigned sA64[2304];   // bf16 [64 rows][72] (stride 36 words, 16B-aligned rows)
    __shared__ unsigned sP64[2304];
    __shared__ float s_w[512];
    __shared__ float s_bias[384];     // sap_b | av_b | f1_b | f2_w
    __shared__ float s_ub[256];       // u | se_b
    const int t = threadIdx.x;
    const int wv = t>>6, lane = t&63;
    const int g = lane>>4, c = lane&15;

    // ===== block-wide tiny staging (one barrier) =====
    float* c_w1 = (float*)(SM+5120);   // 432
    float* c_b1 = (float*)(SM+5552);   // 16
    float* c_b2 = (float*)(SM+5568);   // 32 (ends 5600; hpk ends at 5120)
    for (int q=t; q<432; q+=256) c_w1[q] = w1[q];
    if (t<16) c_b1[t] = b1[t];
    if (t<32) c_b2[t] = b2[t];
    for (int q=t; q<384; q+=256)
        s_bias[q] = (q<128)? sap_b[q] : (q<256)? av_b[q-128] : (q<320)? f1_b[q-256] : f2_w[q-320];
    s_ub[t] = (t<128)? ((const float*)ws)[OFF_U+t] : se_b[t-128];
    __syncthreads();

    // ===== Phase C: conv encoder, fully per-wave (no block barriers) =====
    {
        unsigned* hpk = SM + wv*1280;            // this wave's bf16 B-pack [16 ag][K=160]
        unsigned short* hp16 = (unsigned short*)hpk;
        const int ag = lane&15, ocb = lane>>4;   // lane handles agent ag, oc in {ocb, +4, +8, +12}
        const size_t a0g = (size_t)blockIdx.x*64 + wv*16;
        hpk[1152+lane] = 0;                      // zero K-pad 144..159
        hpk[1216+lane] = 0;
        const float* xrow = xin + (a0g+ag)*75;
        // two halves of 2 oc each (keeps live set small: out[2][9]+pin[25]+w9)
        #pragma unroll
        for (int half=0; half<2; ++half){
            float out[2][9];
            #pragma unroll
            for (int j=0;j<2;++j){
                float bb = c_b1[ocb + (half*2+j)*4];
                #pragma unroll
                for (int p=0;p<9;++p) out[j][p]=bb;
            }
            #pragma unroll
            for (int ic=0;ic<3;++ic){
                float pin[25];
                #pragma unroll
                for (int i=0;i<25;++i) pin[i] = xrow[ic*25+i];
                #pragma unroll
                for (int j=0;j<2;++j){
                    const float* wp = &c_w1[(ocb+(half*2+j)*4)*27 + ic*9];
                    float w9[9];
                    #pragma unroll
                    for (int i=0;i<9;++i) w9[i]=wp[i];
                    #pragma unroll
                    for (int y=0;y<3;++y)
                      #pragma unroll
                      for (int x=0;x<3;++x)
                        #pragma unroll
                        for (int ky=0;ky<3;++ky)
                          #pragma unroll
                          for (int kx=0;kx<3;++kx)
                            out[j][y*3+x] += pin[(y+ky)*5+(x+kx)] * w9[ky*3+kx];
                }
            }
            #pragma unroll
            for (int j=0;j<2;++j){
                const int oc = ocb + (half*2+j)*4;
                #pragma unroll
                for (int p=0;p<9;++p){
                    float v = out[j][p];
                    v = (v>=0.f)? v : 0.01f*v;
                    int k = oc*9+p;
                    int word = (k>>3)*64 + ag*4 + ((k>>1)&3);
                    hp16[word*2 + (k&1)] = (unsigned short)bfr(v);
                }
            }
        }
        // pose/act/pol pack words (ft 4..7): lane = (r = lane&15, ft4 = lane>>4)
        {
            const int r = lane&15, ft4 = lane>>4;
            const size_t row = a0g + r;
            #pragma unroll
            for (int wi=0; wi<4; ++wi){
                int f0 = 32 + ft4*8 + wi*2;
                float a0=0.f,a1=0.f,p0=0.f,p1=0.f;
                if (f0 < 42){ float v = (f0<34)? pos[row*2+(f0-32)] : oneh[row*8+(f0-34)]; a0=v; p0=v; }
                else if (f0 < 47){ a0 = acts[row*5+(f0-42)]; p0 = pols[row*5+(f0-42)]; }
                int f1i = f0+1;
                if (f1i < 42){ float v = (f1i<34)? pos[row*2+(f1i-32)] : oneh[row*8+(f1i-34)]; a1=v; p1=v; }
                else if (f1i < 47){ a1 = acts[row*5+(f1i-42)]; p1 = pols[row*5+(f1i-42)]; }
                int word = wv*512 + (4+ft4)*64 + r*4 + wi;
                stPk[word]      = pk2(a0,a1);
                stPk[2048+word] = pk2(p0,p1);
            }
        }
        // wave-level LDS fence: all lanes' hpk writes complete before conv2 reads
        asm volatile("s_waitcnt lgkmcnt(0)" ::: "memory");
        __builtin_amdgcn_sched_barrier(0);
        // conv2 as MFMA: [16 ag] x [32 oc] x K=160
        f32x4 c2[2];
        c2[0] = (f32x4){0.f,0.f,0.f,0.f};
        c2[1] = (f32x4){0.f,0.f,0.f,0.f};
        #pragma unroll
        for (int kt=0; kt<5; ++kt){
            short8 hb  = fragld(hpk + kt*256 + lane*4);
            short8 w0f = fragld(ws + OFF_W2P + kt*256 + lane*4);
            short8 w1f = fragld(ws + OFF_W2P + 1280 + kt*256 + lane*4);
            c2[0] = MFMA(w0f, hb, c2[0]);
            c2[1] = MFMA(w1f, hb, c2[1]);
        }
        #pragma unroll
        for (int ft=0; ft<2; ++ft){
            const float* bp = &c_b2[ft*16 + g*4];
            float d0 = c2[ft][0]+bp[0]; d0 = (d0>=0.f)? d0 : 0.01f*d0;
            float d1 = c2[ft][1]+bp[1]; d1 = (d1>=0.f)? d1 : 0.01f*d1;
            float d2 = c2[ft][2]+bp[2]; d2 = (d2>=0.f)? d2 : 0.01f*d2;
            float d3 = c2[ft][3]+bp[3]; d3 = (d3>=0.f)? d3 : 0.01f*d3;
            int word = wv*512 + (2*ft + (g>>1))*64 + c*4 + (g&1)*2;
            uint2 pw = make_uint2(pk2(d0,d1), pk2(d2,d3));
            *(uint2*)&stPk[word] = pw;
            *(uint2*)&stPk[2048+word] = pw;
        }
    }
    __syncthreads();   // conv regions die; SM becomes AB stage/scratch

    // ===== Phase AB =====
    const int tile = blockIdx.x*4 + wv;
    short8 bfA0 = fragld(&stPk[wv*512 + lane*4]);
    short8 bfA1 = fragld(&stPk[wv*512 + 256 + lane*4]);
    short8 bfP0 = fragld(&stPk[2048 + wv*512 + lane*4]);
    short8 bfP1 = fragld(&stPk[2048 + wv*512 + 256 + lane*4]);
    unsigned (*s_stage)[2048] = (unsigned (*)[2048])&SM[0];
    unsigned* U1 = &SM[4096];
    unsigned* wS = &U1[wv*1280];          // 1024-word per-wave repack scratch
    unsigned* tS = &U1[wv*1280 + 1024];   // 256-word T scratch

    uint4 r0, r1;
#define PREF(off) { r0 = *(const uint4*)(ws + (off) + t*4); \
                    r1 = *(const uint4*)(ws + (off) + 1024 + t*4); }
#define WR(b) { *(uint4*)&s_stage[b][t*4] = r0; *(uint4*)&s_stage[b][1024 + t*4] = r1; }

    PREF(OFF_SE); WR(0);
    __syncthreads();

    // ---- SE chunks c0,c1 -> acc[8] ----
    f32x4 acc[8];
    #pragma unroll
    for (int i=0;i<8;++i) acc[i] = (f32x4){0.f,0.f,0.f,0.f};
    PREF(OFF_SE + 2048);
    #pragma unroll
    for (int ft=0; ft<4; ++ft){
        short8 a0 = fragld(&s_stage[0][ft*512 + lane*4]);
        short8 a1 = fragld(&s_stage[0][ft*512 + 256 + lane*4]);
        acc[ft] = MFMA(a0, bfA0, acc[ft]);
        acc[ft] = MFMA(a1, bfA1, acc[ft]);
    }
    WR(1); __syncthreads();
    PREF(OFF_M);
    #pragma unroll
    for (int ft=4; ft<8; ++ft){
        short8 a0 = fragld(&s_stage[1][(ft-4)*512 + lane*4]);
        short8 a1 = fragld(&s_stage[1][(ft-4)*512 + 256 + lane*4]);
        acc[ft] = MFMA(a0, bfA0, acc[ft]);
        acc[ft] = MFMA(a1, bfA1, acc[ft]);
    }
    WR(0);
    // E build -> wS, cache ef[4]
    #pragma unroll
    for (int ft=0; ft<8; ++ft){
        const float* bp = &s_ub[128 + ft*16 + g*4];
        float d0 = fast_tanh(acc[ft][0]+bp[0]);
        float d1 = fast_tanh(acc[ft][1]+bp[1]);
        float d2 = fast_tanh(acc[ft][2]+bp[2]);
        float d3 = fast_tanh(acc[ft][3]+bp[3]);
        int word = (2*ft + (g>>1))*64 + c*4 + (g&1)*2;
        *(uint2*)&wS[word] = make_uint2(pk2(d0,d1), pk2(d2,d3));
    }
    short8 ef[4];
    #pragma unroll
    for (int kt=0; kt<4; ++kt) ef[kt] = fragld(&wS[kt*256 + lane*4]);
    __syncthreads();

    // ---- M chunks c2..c5, fused T-write + logits ----
    f32x4 L = (f32x4){0.f,0.f,0.f,0.f};
    #pragma unroll
    for (int i=0; i<4; ++i){
        const int nextOff = (i<3)? (OFF_M + (i+1)*2048) : OFF_SAP;
        PREF(nextOff);
        f32x4 a2[2];
        a2[0] = (f32x4){0.f,0.f,0.f,0.f};
        a2[1] = (f32x4){0.f,0.f,0.f,0.f};
        #pragma unroll
        for (int ftl=0; ftl<2; ++ftl)
          #pragma unroll
          for (int kt=0; kt<4; ++kt){
            short8 mf = fragld(&s_stage[i&1][ftl*1024 + kt*256 + lane*4]);
            a2[ftl] = MFMA(mf, ef[kt], a2[ftl]);
          }
        WR((i+1)&1);
        #pragma unroll
        for (int ftl=0; ftl<2; ++ftl){
            const float* up = &s_ub[(2*i+ftl)*16 + g*4];
            int word = (2*ftl + (g>>1))*64 + c*4 + (g&1)*2;
            *(uint2*)&tS[word] = make_uint2(pk2(a2[ftl][0]+up[0], a2[ftl][1]+up[1]),
                                            pk2(a2[ftl][2]+up[2], a2[ftl][3]+up[3]));
        }
        short8 tf = fragld(&tS[lane*4]);
        L = MFMA(tf, ef[i], L);
        __syncthreads();
    }
    // softmax -> s_w + wout
    {
        float sc[4];
        #pragma unroll
        for (int q=0;q<4;++q) sc[q] = L[q]*0.08838834764831845f;
        #pragma unroll
        for (int q=0;q<4;++q){
            float m = sc[q];
            m = fmaxf(m, __shfl_xor(m,1));
            m = fmaxf(m, __shfl_xor(m,2));
            m = fmaxf(m, __shfl_xor(m,4));
            float ex = __expf(sc[q]-m);
            float su = ex;
            su += __shfl_xor(su,1);
            su += __shfl_xor(su,2);
            su += __shfl_xor(su,4);
            sc[q] = ex/su;
        }
        if ((c>>3) == (g>>1)){
            int lb = wv*2 + (g>>1);
            int batch = tile*2 + (g>>1);
            int idx = ((g&1)*4)*8 + (c&7);
            #pragma unroll
            for (int q=0;q<4;++q){
                float v = sc[q];
                wout[batch*64 + idx + q*8] = v;
                s_w[lb*64 + idx + q*8] = v;
            }
        }
    }

    // ---- SAP chunks c6,c7 -> aS[2][8] ----
    f32x4 aS[2][8];
    #pragma unroll
    for (int v=0;v<2;++v)
      #pragma unroll
      for (int i=0;i<8;++i) aS[v][i] = (f32x4){0.f,0.f,0.f,0.f};
    PREF(OFF_SAP + 2048);
    #pragma unroll
    for (int ft=0; ft<4; ++ft){
        short8 a0 = fragld(&s_stage[0][ft*512 + lane*4]);
        short8 a1 = fragld(&s_stage[0][ft*512 + 256 + lane*4]);
        aS[0][ft] = MFMA(a0, bfA0, aS[0][ft]);
        aS[0][ft] = MFMA(a1, bfA1, aS[0][ft]);
        aS[1][ft] = MFMA(a0, bfP0, aS[1][ft]);
        aS[1][ft] = MFMA(a1, bfP1, aS[1][ft]);
    }
    WR(1); __syncthreads();
    PREF(OFF_AV);
    #pragma unroll
    for (int ft=4; ft<8; ++ft){
        short8 a0 = fragld(&s_stage[1][(ft-4)*512 + lane*4]);
        short8 a1 = fragld(&s_stage[1][(ft-4)*512 + 256 + lane*4]);
        aS[0][ft] = MFMA(a0, bfA0, aS[0][ft]);
        aS[0][ft] = MFMA(a1, bfA1, aS[0][ft]);
        aS[1][ft] = MFMA(a0, bfP0, aS[1][ft]);
        aS[1][ft] = MFMA(a1, bfP1, aS[1][ft]);
    }
    WR(0);
    // SAP build (variant A then P through the single scratch), cache frags
    short8 spA[4], spP[4];
    #pragma unroll
    for (int ft=0; ft<8; ++ft){
        const float* bp = &s_bias[ft*16 + g*4];
        float d0 = fast_tanh(aS[0][ft][0]+bp[0]);
        float d1 = fast_tanh(aS[0][ft][1]+bp[1]);
        float d2 = fast_tanh(aS[0][ft][2]+bp[2]);
        float d3 = fast_tanh(aS[0][ft][3]+bp[3]);
        int word = (2*ft + (g>>1))*64 + c*4 + (g&1)*2;
        *(uint2*)&wS[word] = make_uint2(pk2(d0,d1), pk2(d2,d3));
    }
    #pragma unroll
    for (int kt=0; kt<4; ++kt) spA[kt] = fragld(&wS[kt*256 + lane*4]);
    #pragma unroll
    for (int ft=0; ft<8; ++ft){
        const float* bp = &s_bias[ft*16 + g*4];
        float d0 = fast_tanh(aS[1][ft][0]+bp[0]);
        float d1 = fast_tanh(aS[1][ft][1]+bp[1]);
        float d2 = fast_tanh(aS[1][ft][2]+bp[2]);
        float d3 = fast_tanh(aS[1][ft][3]+bp[3]);
        int word = (2*ft + (g>>1))*64 + c*4 + (g&1)*2;
        *(uint2*)&wS[word] = make_uint2(pk2(d0,d1), pk2(d2,d3));
    }
    #pragma unroll
    for (int kt=0; kt<4; ++kt) spP[kt] = fragld(&wS[kt*256 + lane*4]);
    __syncthreads();

    // ---- AV chunks c8..c11 -> aV[2][8] ----
    f32x4 aV[2][8];
    #pragma unroll
    for (int v=0;v<2;++v)
      #pragma unroll
      for (int i=0;i<8;++i) aV[v][i] = (f32x4){0.f,0.f,0.f,0.f};
    short8 avA[4], avP[4];
    #pragma unroll
    for (int i=0; i<4; ++i){
        const int nextOff = (i<3)? (OFF_AV + (i+1)*2048) : OFF_F1;
        PREF(nextOff);
        #pragma unroll
        for (int ftl=0; ftl<2; ++ftl){
            const int ft = 2*i + ftl;
            #pragma unroll
            for (int kt=0; kt<4; ++kt){
                short8 af = fragld(&s_stage[i&1][ftl*1024 + kt*256 + lane*4]);
                aV[0][ft] = MFMA(af, spA[kt], aV[0][ft]);
                aV[1][ft] = MFMA(af, spP[kt], aV[1][ft]);
            }
        }
        WR((i+1)&1);
        if (i==3){
            // AV build (A then P through scratch), cache frags
            #pragma unroll
            for (int ft=0; ft<8; ++ft){
                const float* bp = &s_bias[128 + ft*16 + g*4];
                float d0 = fast_tanh(aV[0][ft][0]+bp[0]);
                float d1 = fast_tanh(aV[0][ft][1]+bp[1]);
                float d2 = fast_tanh(aV[0][ft][2]+bp[2]);
                float d3 = fast_tanh(aV[0][ft][3]+bp[3]);
                int word = (2*ft + (g>>1))*64 + c*4 + (g&1)*2;
                *(uint2*)&wS[word] = make_uint2(pk2(d0,d1), pk2(d2,d3));
            }
            #pragma unroll
            for (int kt=0; kt<4; ++kt) avA[kt] = fragld(&wS[kt*256 + lane*4]);
            #pragma unroll
            for (int ft=0; ft<8; ++ft){
                const float* bp = &s_bias[128 + ft*16 + g*4];
                float d0 = fast_tanh(aV[1][ft][0]+bp[0]);
                float d1 = fast_tanh(aV[1][ft][1]+bp[1]);
                float d2 = fast_tanh(aV[1][ft][2]+bp[2]);
                float d3 = fast_tanh(aV[1][ft][3]+bp[3]);
                int word = (2*ft + (g>>1))*64 + c*4 + (g&1)*2;
                *(uint2*)&wS[word] = make_uint2(pk2(d0,d1), pk2(d2,d3));
            }
            #pragma unroll
            for (int kt=0; kt<4; ++kt) avP[kt] = fragld(&wS[kt*256 + lane*4]);
        }
        __syncthreads();
    }

    // ---- F1 chunks c12,c13 -> aF[2][4] ----
    f32x4 aF[2][4];
    #pragma unroll
    for (int v=0;v<2;++v)
      #pragma unroll
      for (int i=0;i<4;++i) aF[v][i] = (f32x4){0.f,0.f,0.f,0.f};
    PREF(OFF_F1 + 2048);
    #pragma unroll
    for (int ftl=0; ftl<2; ++ftl)
      #pragma unroll
      for (int kt=0; kt<4; ++kt){
        short8 af = fragld(&s_stage[0][ftl*1024 + kt*256 + lane*4]);
        aF[0][ftl] = MFMA(af, avA[kt], aF[0][ftl]);
        aF[1][ftl] = MFMA(af, avP[kt], aF[1][ftl]);
      }
    WR(1); __syncthreads();
    #pragma unroll
    for (int ftl=0; ftl<2; ++ftl)
      #pragma unroll
      for (int kt=0; kt<4; ++kt){
        short8 af = fragld(&s_stage[1][ftl*1024 + kt*256 + lane*4]);
        aF[0][2+ftl] = MFMA(af, avA[kt], aF[0][2+ftl]);
        aF[1][2+ftl] = MFMA(af, avP[kt], aF[1][2+ftl]);
      }
    {
        int row = wv*16 + c;
        #pragma unroll
        for (int v=0;v<2;++v){
            unsigned* dst = v? sP64 : sA64;
            #pragma unroll
            for (int ft=0; ft<4; ++ft){
                int idx = row*36 + ft*8 + 2*g;
                *(uint2*)&dst[idx] = make_uint2(pk2(aF[v][ft][0], aF[v][ft][1]),
                                                pk2(aF[v][ft][2], aF[v][ft][3]));
            }
        }
    }
    __syncthreads();
    // ---- tail: b64 (vectorized) + final mix (vectorized) ----
    float* s_b64 = (float*)U1;  // [64 rows][68] floats = 4352 words <= 5120
    {
        const int bqa = t>>2, ccg = t&3;
        const int bq = bqa>>3, a = bqa&7;
        const float* wp = &s_w[bq*64 + a*8];
        f32x4 av0 = (f32x4){0.f,0.f,0.f,0.f};
        f32x4 av1 = (f32x4){0.f,0.f,0.f,0.f};
        f32x4 av2 = (f32x4){0.f,0.f,0.f,0.f};
        f32x4 av3 = (f32x4){0.f,0.f,0.f,0.f};
        #pragma unroll
        for (int j=0;j<8;++j){
            float wj = wp[j];
            const unsigned* rp = &sA64[(bq*8+j)*36 + ccg*8];
            short8 v0 = fragld(rp);
            short8 v1 = fragld(rp+4);
            av0[0] += wj*bf2f((unsigned short)v0[0]); av0[1] += wj*bf2f((unsigned short)v0[1]);
            av0[2] += wj*bf2f((unsigned short)v0[2]); av0[3] += wj*bf2f((unsigned short)v0[3]);
            av1[0] += wj*bf2f((unsigned short)v0[4]); av1[1] += wj*bf2f((unsigned short)v0[5]);
            av1[2] += wj*bf2f((unsigned short)v0[6]); av1[3] += wj*bf2f((unsigned short)v0[7]);
            av2[0] += wj*bf2f((unsigned short)v1[0]); av2[1] += wj*bf2f((unsigned short)v1[1]);
            av2[2] += wj*bf2f((unsigned short)v1[2]); av2[3] += wj*bf2f((unsigned short)v1[3]);
            av3[0] += wj*bf2f((unsigned short)v1[4]); av3[1] += wj*bf2f((unsigned short)v1[5]);
            av3[2] += wj*bf2f((unsigned short)v1[6]); av3[3] += wj*bf2f((unsigned short)v1[7]);
        }
        float* outp = &s_b64[bqa*68 + ccg*16];
        *(f32x4*)&outp[0]  = av0;
        *(f32x4*)&outp[4]  = av1;
        *(f32x4*)&outp[8]  = av2;
        *(f32x4*)&outp[12] = av3;
    }
    __syncthreads();
    #pragma unroll
    for (int k=0; k<2; ++k){
        int o = t + 256*k;
        int bq = o>>6, a = (o>>3)&7, i = o&7;
        float w_ai = s_w[bq*64 + a*8 + i];
        const float* pb = &s_b64[(bq*8+a)*68];
        const unsigned* pA = &sA64[(bq*8+i)*36];
        const unsigned* pP = &sP64[(bq*8+i)*36];
        float acc5 = 0.f;
        #pragma unroll
        for (int c8=0; c8<8; ++c8){
            f32x4 pb0 = *(const f32x4*)&pb[c8*8];
            f32x4 pb1 = *(const f32x4*)&pb[c8*8+4];
            short8 va = fragld(pA + c8*4);
            short8 vp = fragld(pP + c8*4);
            const float* fb = &s_bias[256 + c8*8];
            const float* fw = &s_bias[320 + c8*8];
            #pragma unroll
            for (int e=0;e<4;++e){
                float dd = bf2f((unsigned short)vp[e]) - bf2f((unsigned short)va[e]);
                acc5 += fast_tanh(pb0[e] + w_ai*dd + fb[e]) * fw[e];
            }
            #pragma unroll
            for (int e=0;e<4;++e){
                float dd = bf2f((unsigned short)vp[4+e]) - bf2f((unsigned short)va[4+e]);
                acc5 += fast_tanh(pb1[e] + w_ai*dd + fb[4+e]) * fw[4+e];
            }
        }
        value[(size_t)blockIdx.x*512 + o] = acc5 + f2_b[0];
    }
#undef PREF
#undef WR
}

extern "C" void kernel_launch(void* const* d_in, const int* in_sizes, int n_in,
                              void* d_out, int out_size, void* d_ws, size_t ws_size,
                              hipStream_t stream){
    const float* agent_states = (const float*)d_in[0];
    const float* pos    = (const float*)d_in[1];
    const float* oneh   = (const float*)d_in[2];
    const float* pols   = (const float*)d_in[3];
    const float* acts   = (const float*)d_in[4];
    const float* w1     = (const float*)d_in[5];
    const float* b1     = (const float*)d_in[6];
    const float* w2     = (const float*)d_in[7];
    const float* b2     = (const float*)d_in[8];
    const float* se_w   = (const float*)d_in[9];
    const float* se_b   = (const float*)d_in[10];
    const float* key_w  = (const float*)d_in[11];
    const float* query_w= (const float*)d_in[13];
    const float* query_b= (const float*)d_in[14];
    const float* sap_w  = (const float*)d_in[15];
    const float* sap_b  = (const float*)d_in[16];
    const float* av_w   = (const float*)d_in[17];
    const float* av_b   = (const float*)d_in[18];
    const float* f1_w   = (const float*)d_in[19];
    const float* f1_b   = (const float*)d_in[20];
    const float* f2_w   = (const float*)d_in[21];
    const float* f2_b   = (const float*)d_in[22];

    unsigned* ws = (unsigned*)d_ws;

    float* value = (float*)d_out;
    float* wout  = value + (size_t)NB*NA*NA;

    kW<<<123, 256, 0, stream>>>(se_w, sap_w, av_w, f1_w, query_w, key_w, query_b, w2, ws);
    kF<<<BN/64, 256, 0, stream>>>(ws, agent_states, pos, oneh, acts, pols,
                                  w1, b1, b2, se_b, sap_b, av_b, f1_b, f2_w, f2_b,
                                  wout, value);
}

// Round 15
// 51.565 us; speedup vs baseline: 1.0067x; 1.0067x over previous
//
#include <hip/hip_runtime.h>
#include <math.h>

#define NB 4096
#define NA 8
#define BN (NB*NA)   // 32768

// ws layout (u32 words)
#define OFF_SE   0            // se pack:  8 tiles * 512
#define OFF_SAP  4096         // sap pack: 8 tiles * 512
#define OFF_AV   8192         // av pack:  8 tiles * 1024
#define OFF_F1   16384        // f1 pack:  4 tiles * 1024
#define OFF_M    20480        // M pack:   8 tiles * 1024
#define OFF_U    28672        // u: 128 floats
#define OFF_W2P  28800        // conv2 weight A-frag pack: 2 ftiles * 1280 (K=160 pad)
// ws end: 31360 words

typedef short short8 __attribute__((ext_vector_type(8)));
typedef float f32x4 __attribute__((ext_vector_type(4)));

#define MFMA(a,b,c) __builtin_amdgcn_mfma_f32_16x16x32_bf16(a,b,c,0,0,0)
#define PRIO1() __builtin_amdgcn_s_setprio(1)
#define PRIO0() __builtin_amdgcn_s_setprio(0)

__device__ __forceinline__ float fast_tanh(float x){
    float e = __expf(2.0f*x);
    return 1.0f - 2.0f*__builtin_amdgcn_rcpf(e+1.0f);
}
__device__ __forceinline__ unsigned bfr(float x){
    unsigned u = __float_as_uint(x);
    return (u + 0x7fffu + ((u>>16)&1u)) >> 16;
}
__device__ __forceinline__ unsigned pk2(float lo, float hi){
    return bfr(lo) | (bfr(hi)<<16);
}
__device__ __forceinline__ float bf2f(unsigned short s){
    return __uint_as_float(((unsigned)s)<<16);
}
__device__ __forceinline__ short8 fragld(const unsigned* p){
    union { uint4 u; short8 s; } cv;
    cv.u = *(const uint4*)p;
    return cv.s;
}

// ---------------- kW: pack all weights as A-fragments (pack16 of W^T), compute M, u, w2 pack
__global__ __launch_bounds__(256) void kW(const float* __restrict__ se_w,
        const float* __restrict__ sap_w, const float* __restrict__ av_w,
        const float* __restrict__ f1_w, const float* __restrict__ qw,
        const float* __restrict__ kw, const float* __restrict__ qb,
        const float* __restrict__ w2,
        unsigned* __restrict__ ws){
    int idx = blockIdx.x*256 + threadIdx.x;
    if (idx < 4096){                       // sePk (F=64 pad, rows f2=128)
        int w = idx, tile = w>>9, rem = w&511;
        int ft = rem>>6, r2 = (rem>>2)&15, wi = rem&3;
        int f2 = tile*16 + r2, f1 = ft*8 + wi*2;
        float lo = (f1   < 42)? se_w[f1*128+f2]     : 0.f;
        float hi = (f1+1 < 42)? se_w[(f1+1)*128+f2] : 0.f;
        ws[OFF_SE + w] = pk2(lo,hi);
    } else if (idx < 8192){                // sapPk (F=64 pad, limit 47)
        int w = idx-4096, tile = w>>9, rem = w&511;
        int ft = rem>>6, r2 = (rem>>2)&15, wi = rem&3;
        int f2 = tile*16 + r2, f1 = ft*8 + wi*2;
        float lo = (f1   < 47)? sap_w[f1*128+f2]     : 0.f;
        float hi = (f1+1 < 47)? sap_w[(f1+1)*128+f2] : 0.f;
        ws[OFF_SAP + w] = pk2(lo,hi);
    } else if (idx < 16384){               // avPk (F=128)
        int w = idx-8192, tile = w>>10, rem = w&1023;
        int ft = rem>>6, r2 = (rem>>2)&15, wi = rem&3;
        int f2 = tile*16 + r2, f1 = ft*8 + wi*2;
        ws[OFF_AV + w] = pk2(av_w[f1*128+f2], av_w[(f1+1)*128+f2]);
    } else if (idx < 20480){               // f1Pk (F=128, rows f2=64)
        int w = idx-16384, tile = w>>10, rem = w&1023;
        int ft = rem>>6, r2 = (rem>>2)&15, wi = rem&3;
        int f2 = tile*16 + r2, f1 = ft*8 + wi*2;
        ws[OFF_F1 + w] = pk2(f1_w[f1*64+f2], f1_w[(f1+1)*64+f2]);
    } else if (idx < 28672){               // MPk: M[e][f2] = qw[e]·kw[f2]
        int w = idx-20480, tile = w>>10, rem = w&1023;
        int ft = rem>>6, r2 = (rem>>2)&15, wi = rem&3;
        int f2 = tile*16 + r2, e0 = ft*8 + wi*2;
        float lo=0.f, hi=0.f;
        for (int d=0; d<128; ++d){
            float kv = kw[f2*128+d];
            lo += qw[e0*128+d]*kv;
            hi += qw[(e0+1)*128+d]*kv;
        }
        ws[OFF_M + w] = pk2(lo,hi);
    } else if (idx < 28800){               // u[f] = qb·kw[f]
        int f = idx-28672;
        float a = 0.f;
        for (int d=0; d<128; ++d) a += qb[d]*kw[f*128+d];
        ((float*)ws)[OFF_U + f] = a;
    } else if (idx < 31360){               // conv2 weight A-frags: F=32, K=160 (pad from 144)
        int w = idx-28800;
        int ftile = w/1280, rem = w - ftile*1280;
        int ft = rem>>6, r2 = (rem>>2)&15, wi = rem&3;
        int f = ftile*16 + r2, k0 = ft*8 + wi*2;
        float lo = (k0   < 144)? w2[f*144+k0]   : 0.f;
        float hi = (k0+1 < 144)? w2[f*144+k0+1] : 0.f;
        ws[OFF_W2P + w] = pk2(lo,hi);
    }
}

// ---------------- kF: barrier-free per-wave conv + fused attention/SAP/AV/f1/mix ----------
// grid 512, 256 threads = 4 waves = 4 tiles = 64 agents = 8 batches per block.
__global__ __launch_bounds__(256,2) void kF(const unsigned* __restrict__ ws,
        const float* __restrict__ xin, const float* __restrict__ pos,
        const float* __restrict__ oneh, const float* __restrict__ acts,
        const float* __restrict__ pols,
        const float* __restrict__ w1, const float* __restrict__ b1,
        const float* __restrict__ b2,
        const float* __restrict__ se_b,
        const float* __restrict__ sap_b, const float* __restrict__ av_b,
        const float* __restrict__ f1_b, const float* __restrict__ f2_w,
        const float* __restrict__ f2_b,
        float* __restrict__ wout, float* __restrict__ value){
    __shared__ unsigned SM[9216];     // conv: hpk[4*1280] + w1/b1/b2 @5120 ; AB: stage[2][2048]+U1[5120]
    __shared__ unsigned stPk[4096];   // persistent state packs: A[4*512] | P[4*512]
    __shared__ unsigned sA64[2304];   // bf16 [64 rows][72] (stride 36 words, 16B-aligned rows)
    __shared__ unsigned sP64[2304];
    __shared__ float s_w[512];
    __shared__ float s_bias[384];     // sap_b | av_b | f1_b | f2_w
    __shared__ float s_ub[256];       // u | se_b
    const int t = threadIdx.x;
    const int wv = t>>6, lane = t&63;
    const int g = lane>>4, c = lane&15;

    // ===== block-wide tiny staging (one barrier) =====
    float* c_w1 = (float*)(SM+5120);   // 432
    float* c_b1 = (float*)(SM+5552);   // 16
    float* c_b2 = (float*)(SM+5568);   // 32 (ends 5600; hpk ends at 5120)
    for (int q=t; q<432; q+=256) c_w1[q] = w1[q];
    if (t<16) c_b1[t] = b1[t];
    if (t<32) c_b2[t] = b2[t];
    for (int q=t; q<384; q+=256)
        s_bias[q] = (q<128)? sap_b[q] : (q<256)? av_b[q-128] : (q<320)? f1_b[q-256] : f2_w[q-320];
    s_ub[t] = (t<128)? ((const float*)ws)[OFF_U+t] : se_b[t-128];
    __syncthreads();

    // issue-early SE stage prefetch (rides out under conv compute)
    uint4 r0, r1;
#define PREF(off) { r0 = *(const uint4*)(ws + (off) + t*4); \
                    r1 = *(const uint4*)(ws + (off) + 1024 + t*4); }
#define WR(b) { *(uint4*)&s_stage[b][t*4] = r0; *(uint4*)&s_stage[b][1024 + t*4] = r1; }
    PREF(OFF_SE);

    // ===== Phase C: conv encoder, fully per-wave (no block barriers) =====
    {
        unsigned* hpk = SM + wv*1280;            // this wave's bf16 B-pack [16 ag][K=160]
        unsigned short* hp16 = (unsigned short*)hpk;
        const int ag = lane&15, ocb = lane>>4;   // lane handles agent ag, oc in {ocb, +4, +8, +12}
        const size_t a0g = (size_t)blockIdx.x*64 + wv*16;
        hpk[1152+lane] = 0;                      // zero K-pad 144..159
        hpk[1216+lane] = 0;
        const float* xrow = xin + (a0g+ag)*75;
        // two halves of 2 oc each (keeps live set small: out[2][9]+pin[25]+w9)
        #pragma unroll
        for (int half=0; half<2; ++half){
            float out[2][9];
            #pragma unroll
            for (int j=0;j<2;++j){
                float bb = c_b1[ocb + (half*2+j)*4];
                #pragma unroll
                for (int p=0;p<9;++p) out[j][p]=bb;
            }
            #pragma unroll
            for (int ic=0;ic<3;++ic){
                float pin[25];
                #pragma unroll
                for (int i=0;i<25;++i) pin[i] = xrow[ic*25+i];
                #pragma unroll
                for (int j=0;j<2;++j){
                    const float* wp = &c_w1[(ocb+(half*2+j)*4)*27 + ic*9];
                    float w9[9];
                    #pragma unroll
                    for (int i=0;i<9;++i) w9[i]=wp[i];
                    #pragma unroll
                    for (int y=0;y<3;++y)
                      #pragma unroll
                      for (int x=0;x<3;++x)
                        #pragma unroll
                        for (int ky=0;ky<3;++ky)
                          #pragma unroll
                          for (int kx=0;kx<3;++kx)
                            out[j][y*3+x] += pin[(y+ky)*5+(x+kx)] * w9[ky*3+kx];
                }
            }
            #pragma unroll
            for (int j=0;j<2;++j){
                const int oc = ocb + (half*2+j)*4;
                #pragma unroll
                for (int p=0;p<9;++p){
                    float v = out[j][p];
                    v = (v>=0.f)? v : 0.01f*v;
                    int k = oc*9+p;
                    int word = (k>>3)*64 + ag*4 + ((k>>1)&3);
                    hp16[word*2 + (k&1)] = (unsigned short)bfr(v);
                }
            }
        }
        // pose/act/pol pack words (ft 4..7): lane = (r = lane&15, ft4 = lane>>4)
        {
            const int r = lane&15, ft4 = lane>>4;
            const size_t row = a0g + r;
            #pragma unroll
            for (int wi=0; wi<4; ++wi){
                int f0 = 32 + ft4*8 + wi*2;
                float a0=0.f,a1=0.f,p0=0.f,p1=0.f;
                if (f0 < 42){ float v = (f0<34)? pos[row*2+(f0-32)] : oneh[row*8+(f0-34)]; a0=v; p0=v; }
                else if (f0 < 47){ a0 = acts[row*5+(f0-42)]; p0 = pols[row*5+(f0-42)]; }
                int f1i = f0+1;
                if (f1i < 42){ float v = (f1i<34)? pos[row*2+(f1i-32)] : oneh[row*8+(f1i-34)]; a1=v; p1=v; }
                else if (f1i < 47){ a1 = acts[row*5+(f1i-42)]; p1 = pols[row*5+(f1i-42)]; }
                int word = wv*512 + (4+ft4)*64 + r*4 + wi;
                stPk[word]      = pk2(a0,a1);
                stPk[2048+word] = pk2(p0,p1);
            }
        }
        // wave-level LDS fence: all lanes' hpk writes complete before conv2 reads
        asm volatile("s_waitcnt lgkmcnt(0)" ::: "memory");
        __builtin_amdgcn_sched_barrier(0);
        // conv2 as MFMA: [16 ag] x [32 oc] x K=160
        f32x4 c2[2];
        c2[0] = (f32x4){0.f,0.f,0.f,0.f};
        c2[1] = (f32x4){0.f,0.f,0.f,0.f};
        PRIO1();
        #pragma unroll
        for (int kt=0; kt<5; ++kt){
            short8 hb  = fragld(hpk + kt*256 + lane*4);
            short8 w0f = fragld(ws + OFF_W2P + kt*256 + lane*4);
            short8 w1f = fragld(ws + OFF_W2P + 1280 + kt*256 + lane*4);
            c2[0] = MFMA(w0f, hb, c2[0]);
            c2[1] = MFMA(w1f, hb, c2[1]);
        }
        PRIO0();
        #pragma unroll
        for (int ft=0; ft<2; ++ft){
            const float* bp = &c_b2[ft*16 + g*4];
            float d0 = c2[ft][0]+bp[0]; d0 = (d0>=0.f)? d0 : 0.01f*d0;
            float d1 = c2[ft][1]+bp[1]; d1 = (d1>=0.f)? d1 : 0.01f*d1;
            float d2 = c2[ft][2]+bp[2]; d2 = (d2>=0.f)? d2 : 0.01f*d2;
            float d3 = c2[ft][3]+bp[3]; d3 = (d3>=0.f)? d3 : 0.01f*d3;
            int word = wv*512 + (2*ft + (g>>1))*64 + c*4 + (g&1)*2;
            uint2 pw = make_uint2(pk2(d0,d1), pk2(d2,d3));
            *(uint2*)&stPk[word] = pw;
            *(uint2*)&stPk[2048+word] = pw;
        }
    }
    __syncthreads();   // conv regions die; SM becomes AB stage/scratch

    // ===== Phase AB =====
    const int tile = blockIdx.x*4 + wv;
    short8 bfA0 = fragld(&stPk[wv*512 + lane*4]);
    short8 bfA1 = fragld(&stPk[wv*512 + 256 + lane*4]);
    short8 bfP0 = fragld(&stPk[2048 + wv*512 + lane*4]);
    short8 bfP1 = fragld(&stPk[2048 + wv*512 + 256 + lane*4]);
    unsigned (*s_stage)[2048] = (unsigned (*)[2048])&SM[0];
    unsigned* U1 = &SM[4096];
    unsigned* wS = &U1[wv*1280];          // 1024-word per-wave repack scratch
    unsigned* tS = &U1[wv*1280 + 1024];   // 256-word T scratch

    WR(0);                 // SE chunk 0 (prefetched before conv)
    PREF(OFF_SE + 2048);
    __syncthreads();

    // ---- SE chunks c0,c1 -> acc[8] ----
    f32x4 acc[8];
    #pragma unroll
    for (int i=0;i<8;++i) acc[i] = (f32x4){0.f,0.f,0.f,0.f};
    PRIO1();
    #pragma unroll
    for (int ft=0; ft<4; ++ft){
        short8 a0 = fragld(&s_stage[0][ft*512 + lane*4]);
        short8 a1 = fragld(&s_stage[0][ft*512 + 256 + lane*4]);
        acc[ft] = MFMA(a0, bfA0, acc[ft]);
        acc[ft] = MFMA(a1, bfA1, acc[ft]);
    }
    PRIO0();
    WR(1); __syncthreads();
    PREF(OFF_M);
    PRIO1();
    #pragma unroll
    for (int ft=4; ft<8; ++ft){
        short8 a0 = fragld(&s_stage[1][(ft-4)*512 + lane*4]);
        short8 a1 = fragld(&s_stage[1][(ft-4)*512 + 256 + lane*4]);
        acc[ft] = MFMA(a0, bfA0, acc[ft]);
        acc[ft] = MFMA(a1, bfA1, acc[ft]);
    }
    PRIO0();
    WR(0);
    // E build -> wS, cache ef[4]
    #pragma unroll
    for (int ft=0; ft<8; ++ft){
        const float* bp = &s_ub[128 + ft*16 + g*4];
        float d0 = fast_tanh(acc[ft][0]+bp[0]);
        float d1 = fast_tanh(acc[ft][1]+bp[1]);
        float d2 = fast_tanh(acc[ft][2]+bp[2]);
        float d3 = fast_tanh(acc[ft][3]+bp[3]);
        int word = (2*ft + (g>>1))*64 + c*4 + (g&1)*2;
        *(uint2*)&wS[word] = make_uint2(pk2(d0,d1), pk2(d2,d3));
    }
    short8 ef[4];
    #pragma unroll
    for (int kt=0; kt<4; ++kt) ef[kt] = fragld(&wS[kt*256 + lane*4]);
    __syncthreads();

    // ---- M chunks c2..c5, fused T-write + logits ----
    f32x4 L = (f32x4){0.f,0.f,0.f,0.f};
    #pragma unroll
    for (int i=0; i<4; ++i){
        const int nextOff = (i<3)? (OFF_M + (i+1)*2048) : OFF_SAP;
        PREF(nextOff);
        f32x4 a2[2];
        a2[0] = (f32x4){0.f,0.f,0.f,0.f};
        a2[1] = (f32x4){0.f,0.f,0.f,0.f};
        PRIO1();
        #pragma unroll
        for (int ftl=0; ftl<2; ++ftl)
          #pragma unroll
          for (int kt=0; kt<4; ++kt){
            short8 mf = fragld(&s_stage[i&1][ftl*1024 + kt*256 + lane*4]);
            a2[ftl] = MFMA(mf, ef[kt], a2[ftl]);
          }
        PRIO0();
        WR((i+1)&1);
        #pragma unroll
        for (int ftl=0; ftl<2; ++ftl){
            const float* up = &s_ub[(2*i+ftl)*16 + g*4];
            int word = (2*ftl + (g>>1))*64 + c*4 + (g&1)*2;
            *(uint2*)&tS[word] = make_uint2(pk2(a2[ftl][0]+up[0], a2[ftl][1]+up[1]),
                                            pk2(a2[ftl][2]+up[2], a2[ftl][3]+up[3]));
        }
        short8 tf = fragld(&tS[lane*4]);
        L = MFMA(tf, ef[i], L);
        __syncthreads();
    }
    // softmax -> s_w + wout
    {
        float sc[4];
        #pragma unroll
        for (int q=0;q<4;++q) sc[q] = L[q]*0.08838834764831845f;
        #pragma unroll
        for (int q=0;q<4;++q){
            float m = sc[q];
            m = fmaxf(m, __shfl_xor(m,1));
            m = fmaxf(m, __shfl_xor(m,2));
            m = fmaxf(m, __shfl_xor(m,4));
            float ex = __expf(sc[q]-m);
            float su = ex;
            su += __shfl_xor(su,1);
            su += __shfl_xor(su,2);
            su += __shfl_xor(su,4);
            sc[q] = ex/su;
        }
        if ((c>>3) == (g>>1)){
            int lb = wv*2 + (g>>1);
            int batch = tile*2 + (g>>1);
            int idx = ((g&1)*4)*8 + (c&7);
            #pragma unroll
            for (int q=0;q<4;++q){
                float v = sc[q];
                wout[batch*64 + idx + q*8] = v;
                s_w[lb*64 + idx + q*8] = v;
            }
        }
    }

    // ---- SAP chunks c6,c7 -> aS[2][8] ----
    f32x4 aS[2][8];
    #pragma unroll
    for (int v=0;v<2;++v)
      #pragma unroll
      for (int i=0;i<8;++i) aS[v][i] = (f32x4){0.f,0.f,0.f,0.f};
    PREF(OFF_SAP + 2048);
    PRIO1();
    #pragma unroll
    for (int ft=0; ft<4; ++ft){
        short8 a0 = fragld(&s_stage[0][ft*512 + lane*4]);
        short8 a1 = fragld(&s_stage[0][ft*512 + 256 + lane*4]);
        aS[0][ft] = MFMA(a0, bfA0, aS[0][ft]);
        aS[0][ft] = MFMA(a1, bfA1, aS[0][ft]);
        aS[1][ft] = MFMA(a0, bfP0, aS[1][ft]);
        aS[1][ft] = MFMA(a1, bfP1, aS[1][ft]);
    }
    PRIO0();
    WR(1); __syncthreads();
    PREF(OFF_AV);
    PRIO1();
    #pragma unroll
    for (int ft=4; ft<8; ++ft){
        short8 a0 = fragld(&s_stage[1][(ft-4)*512 + lane*4]);
        short8 a1 = fragld(&s_stage[1][(ft-4)*512 + 256 + lane*4]);
        aS[0][ft] = MFMA(a0, bfA0, aS[0][ft]);
        aS[0][ft] = MFMA(a1, bfA1, aS[0][ft]);
        aS[1][ft] = MFMA(a0, bfP0, aS[1][ft]);
        aS[1][ft] = MFMA(a1, bfP1, aS[1][ft]);
    }
    PRIO0();
    WR(0);
    // SAP build (variant A then P through the single scratch), cache frags
    short8 spA[4], spP[4];
    #pragma unroll
    for (int ft=0; ft<8; ++ft){
        const float* bp = &s_bias[ft*16 + g*4];
        float d0 = fast_tanh(aS[0][ft][0]+bp[0]);
        float d1 = fast_tanh(aS[0][ft][1]+bp[1]);
        float d2 = fast_tanh(aS[0][ft][2]+bp[2]);
        float d3 = fast_tanh(aS[0][ft][3]+bp[3]);
        int word = (2*ft + (g>>1))*64 + c*4 + (g&1)*2;
        *(uint2*)&wS[word] = make_uint2(pk2(d0,d1), pk2(d2,d3));
    }
    #pragma unroll
    for (int kt=0; kt<4; ++kt) spA[kt] = fragld(&wS[kt*256 + lane*4]);
    #pragma unroll
    for (int ft=0; ft<8; ++ft){
        const float* bp = &s_bias[ft*16 + g*4];
        float d0 = fast_tanh(aS[1][ft][0]+bp[0]);
        float d1 = fast_tanh(aS[1][ft][1]+bp[1]);
        float d2 = fast_tanh(aS[1][ft][2]+bp[2]);
        float d3 = fast_tanh(aS[1][ft][3]+bp[3]);
        int word = (2*ft + (g>>1))*64 + c*4 + (g&1)*2;
        *(uint2*)&wS[word] = make_uint2(pk2(d0,d1), pk2(d2,d3));
    }
    #pragma unroll
    for (int kt=0; kt<4; ++kt) spP[kt] = fragld(&wS[kt*256 + lane*4]);
    __syncthreads();

    // ---- AV chunks c8..c11 -> aV[2][8] ----
    f32x4 aV[2][8];
    #pragma unroll
    for (int v=0;v<2;++v)
      #pragma unroll
      for (int i=0;i<8;++i) aV[v][i] = (f32x4){0.f,0.f,0.f,0.f};
    short8 avA[4], avP[4];
    #pragma unroll
    for (int i=0; i<4; ++i){
        const int nextOff = (i<3)? (OFF_AV + (i+1)*2048) : OFF_F1;
        PREF(nextOff);
        PRIO1();
        #pragma unroll
        for (int ftl=0; ftl<2; ++ftl){
            const int ft = 2*i + ftl;
            #pragma unroll
            for (int kt=0; kt<4; ++kt){
                short8 af = fragld(&s_stage[i&1][ftl*1024 + kt*256 + lane*4]);
                aV[0][ft] = MFMA(af, spA[kt], aV[0][ft]);
                aV[1][ft] = MFMA(af, spP[kt], aV[1][ft]);
            }
        }
        PRIO0();
        WR((i+1)&1);
        if (i==3){
            // AV build (A then P through scratch), cache frags
            #pragma unroll
            for (int ft=0; ft<8; ++ft){
                const float* bp = &s_bias[128 + ft*16 + g*4];
                float d0 = fast_tanh(aV[0][ft][0]+bp[0]);
                float d1 = fast_tanh(aV[0][ft][1]+bp[1]);
                float d2 = fast_tanh(aV[0][ft][2]+bp[2]);
                float d3 = fast_tanh(aV[0][ft][3]+bp[3]);
                int word = (2*ft + (g>>1))*64 + c*4 + (g&1)*2;
                *(uint2*)&wS[word] = make_uint2(pk2(d0,d1), pk2(d2,d3));
            }
            #pragma unroll
            for (int kt=0; kt<4; ++kt) avA[kt] = fragld(&wS[kt*256 + lane*4]);
            #pragma unroll
            for (int ft=0; ft<8; ++ft){
                const float* bp = &s_bias[128 + ft*16 + g*4];
                float d0 = fast_tanh(aV[1][ft][0]+bp[0]);
                float d1 = fast_tanh(aV[1][ft][1]+bp[1]);
                float d2 = fast_tanh(aV[1][ft][2]+bp[2]);
                float d3 = fast_tanh(aV[1][ft][3]+bp[3]);
                int word = (2*ft + (g>>1))*64 + c*4 + (g&1)*2;
                *(uint2*)&wS[word] = make_uint2(pk2(d0,d1), pk2(d2,d3));
            }
            #pragma unroll
            for (int kt=0; kt<4; ++kt) avP[kt] = fragld(&wS[kt*256 + lane*4]);
        }
        __syncthreads();
    }

    // ---- F1 chunks c12,c13 -> aF[2][4] ----
    f32x4 aF[2][4];
    #pragma unroll
    for (int v=0;v<2;++v)
      #pragma unroll
      for (int i=0;i<4;++i) aF[v][i] = (f32x4){0.f,0.f,0.f,0.f};
    PREF(OFF_F1 + 2048);
    PRIO1();
    #pragma unroll
    for (int ftl=0; ftl<2; ++ftl)
      #pragma unroll
      for (int kt=0; kt<4; ++kt){
        short8 af = fragld(&s_stage[0][ftl*1024 + kt*256 + lane*4]);
        aF[0][ftl] = MFMA(af, avA[kt], aF[0][ftl]);
        aF[1][ftl] = MFMA(af, avP[kt], aF[1][ftl]);
      }
    PRIO0();
    WR(1); __syncthreads();
    PRIO1();
    #pragma unroll
    for (int ftl=0; ftl<2; ++ftl)
      #pragma unroll
      for (int kt=0; kt<4; ++kt){
        short8 af = fragld(&s_stage[1][ftl*1024 + kt*256 + lane*4]);
        aF[0][2+ftl] = MFMA(af, avA[kt], aF[0][2+ftl]);
        aF[1][2+ftl] = MFMA(af, avP[kt], aF[1][2+ftl]);
      }
    PRIO0();
    {
        int row = wv*16 + c;
        #pragma unroll
        for (int v=0;v<2;++v){
            unsigned* dst = v? sP64 : sA64;
            #pragma unroll
            for (int ft=0; ft<4; ++ft){
                int idx = row*36 + ft*8 + 2*g;
                *(uint2*)&dst[idx] = make_uint2(pk2(aF[v][ft][0], aF[v][ft][1]),
                                                pk2(aF[v][ft][2], aF[v][ft][3]));
            }
        }
    }
    __syncthreads();
    // ---- tail: b64 (vectorized) + final mix (vectorized) ----
    float* s_b64 = (float*)U1;  // [64 rows][68] floats = 4352 words <= 5120
    {
        const int bqa = t>>2, ccg = t&3;
        const int bq = bqa>>3, a = bqa&7;
        const float* wp = &s_w[bq*64 + a*8];
        f32x4 av0 = (f32x4){0.f,0.f,0.f,0.f};
        f32x4 av1 = (f32x4){0.f,0.f,0.f,0.f};
        f32x4 av2 = (f32x4){0.f,0.f,0.f,0.f};
        f32x4 av3 = (f32x4){0.f,0.f,0.f,0.f};
        #pragma unroll
        for (int j=0;j<8;++j){
            float wj = wp[j];
            const unsigned* rp = &sA64[(bq*8+j)*36 + ccg*8];
            short8 v0 = fragld(rp);
            short8 v1 = fragld(rp+4);
            av0[0] += wj*bf2f((unsigned short)v0[0]); av0[1] += wj*bf2f((unsigned short)v0[1]);
            av0[2] += wj*bf2f((unsigned short)v0[2]); av0[3] += wj*bf2f((unsigned short)v0[3]);
            av1[0] += wj*bf2f((unsigned short)v0[4]); av1[1] += wj*bf2f((unsigned short)v0[5]);
            av1[2] += wj*bf2f((unsigned short)v0[6]); av1[3] += wj*bf2f((unsigned short)v0[7]);
            av2[0] += wj*bf2f((unsigned short)v1[0]); av2[1] += wj*bf2f((unsigned short)v1[1]);
            av2[2] += wj*bf2f((unsigned short)v1[2]); av2[3] += wj*bf2f((unsigned short)v1[3]);
            av3[0] += wj*bf2f((unsigned short)v1[4]); av3[1] += wj*bf2f((unsigned short)v1[5]);
            av3[2] += wj*bf2f((unsigned short)v1[6]); av3[3] += wj*bf2f((unsigned short)v1[7]);
        }
        float* outp = &s_b64[bqa*68 + ccg*16];
        *(f32x4*)&outp[0]  = av0;
        *(f32x4*)&outp[4]  = av1;
        *(f32x4*)&outp[8]  = av2;
        *(f32x4*)&outp[12] = av3;
    }
    __syncthreads();
    #pragma unroll
    for (int k=0; k<2; ++k){
        int o = t + 256*k;
        int bq = o>>6, a = (o>>3)&7, i = o&7;
        float w_ai = s_w[bq*64 + a*8 + i];
        const float* pb = &s_b64[(bq*8+a)*68];
        const unsigned* pA = &sA64[(bq*8+i)*36];
        const unsigned* pP = &sP64[(bq*8+i)*36];
        float acc5 = 0.f;
        #pragma unroll
        for (int c8=0; c8<8; ++c8){
            f32x4 pb0 = *(const f32x4*)&pb[c8*8];
            f32x4 pb1 = *(const f32x4*)&pb[c8*8+4];
            short8 va = fragld(pA + c8*4);
            short8 vp = fragld(pP + c8*4);
            const float* fb = &s_bias[256 + c8*8];
            const float* fw = &s_bias[320 + c8*8];
            #pragma unroll
            for (int e=0;e<4;++e){
                float dd = bf2f((unsigned short)vp[e]) - bf2f((unsigned short)va[e]);
                acc5 += fast_tanh(pb0[e] + w_ai*dd + fb[e]) * fw[e];
            }
            #pragma unroll
            for (int e=0;e<4;++e){
                float dd = bf2f((unsigned short)vp[4+e]) - bf2f((unsigned short)va[4+e]);
                acc5 += fast_tanh(pb1[e] + w_ai*dd + fb[4+e]) * fw[4+e];
            }
        }
        value[(size_t)blockIdx.x*512 + o] = acc5 + f2_b[0];
    }
#undef PREF
#undef WR
}

extern "C" void kernel_launch(void* const* d_in, const int* in_sizes, int n_in,
                              void* d_out, int out_size, void* d_ws, size_t ws_size,
                              hipStream_t stream){
    const float* agent_states = (const float*)d_in[0];
    const float* pos    = (const float*)d_in[1];
    const float* oneh   = (const float*)d_in[2];
    const float* pols   = (const float*)d_in[3];
    const float* acts   = (const float*)d_in[4];
    const float* w1     = (const float*)d_in[5];
    const float* b1     = (const float*)d_in[6];
    const float* w2     = (const float*)d_in[7];
    const float* b2     = (const float*)d_in[8];
    const float* se_w   = (const float*)d_in[9];
    const float* se_b   = (const float*)d_in[10];
    const float* key_w  = (const float*)d_in[11];
    const float* query_w= (const float*)d_in[13];
    const float* query_b= (const float*)d_in[14];
    const float* sap_w  = (const float*)d_in[15];
    const float* sap_b  = (const float*)d_in[16];
    const float* av_w   = (const float*)d_in[17];
    const float* av_b   = (const float*)d_in[18];
    const float* f1_w   = (const float*)d_in[19];
    const float* f1_b   = (const float*)d_in[20];
    const float* f2_w   = (const float*)d_in[21];
    const float* f2_b   = (const float*)d_in[22];

    unsigned* ws = (unsigned*)d_ws;

    float* value = (float*)d_out;
    float* wout  = value + (size_t)NB*NA*NA;

    kW<<<123, 256, 0, stream>>>(se_w, sap_w, av_w, f1_w, query_w, key_w, query_b, w2, ws);
    kF<<<BN/64, 256, 0, stream>>>(ws, agent_states, pos, oneh, acts, pols,
                                  w1, b1, b2, se_b, sap_b, av_b, f1_b, f2_w, f2_b,
                                  wout, value);
}